// Round 1
// baseline (575.690 us; speedup 1.0000x reference)
//
#include <hip/hip_runtime.h>
#include <hip/hip_bf16.h>
#include <stdint.h>

// RNNPool on MI355X: B=16, S=4096, E=512, window=8.
// Fused design: 256 blocks x 512 threads; each block owns 32 windows and runs
// the whole 8-step tanh RNN with h kept in LDS (bf16 hi+lo split for accuracy).
// Weights are pre-packed into MFMA-fragment-major bf16 (1 MB in d_ws) so every
// B-operand load is a coalesced 1KB global_load_dwordx4 served from L2.

#define E_DIM 512
#define KSIZE 8
#define R_WIN 32           // windows per block
#define NBLK  256          // 8192 windows / 32
#define NTHR  512          // 8 waves

typedef __attribute__((ext_vector_type(8))) short          bf16x8;  // MFMA A/B frag (4 VGPRs)
typedef __attribute__((ext_vector_type(4))) float          f32x4;   // MFMA C/D frag
typedef __attribute__((ext_vector_type(4))) unsigned short u16x4;
typedef __attribute__((ext_vector_type(8))) unsigned short u16x8;

__device__ __forceinline__ unsigned short f2bf(float f) {
  union { float f; uint32_t u; } v; v.f = f;
  uint32_t u = v.u;
  uint32_t r = u + 0x7FFFu + ((u >> 16) & 1u);   // round-to-nearest-even
  return (unsigned short)(r >> 16);
}
__device__ __forceinline__ float bf2f(unsigned short h) {
  union { uint32_t u; float f; } v; v.u = ((uint32_t)h) << 16;
  return v.f;
}
__device__ __forceinline__ float tanh_fast(float v) {
  // 1 - 2/(1+e^{2v}): exact saturation at +/-1, ~1e-7 abs error, 1 v_exp.
  return 1.0f - 2.0f / (1.0f + __expf(2.0f * v));
}

// ---------------------------------------------------------------------------
// Pack W_ih and W_hh (fp32 [out=512][in=512]) into bf16 fragment-major layout
// for mfma_f32_16x16x32_bf16 B-operand:
//   frag(m, n_tile, k_slice): lane l holds W[n_tile*16 + (l&15)][k_slice*32 + (l>>4)*8 + j]
//   byte layout: ((m*32 + n)*16 + s)*512 + l*8   (ushort units)
// Also bias[n] = b_ih[n] + b_hh[n] (fp32) at wpack + 524288 ushorts.
// ---------------------------------------------------------------------------
__global__ void pack_kernel(const float* __restrict__ Wih, const float* __restrict__ Whh,
                            const float* __restrict__ bih, const float* __restrict__ bhh,
                            unsigned short* __restrict__ wpack, float* __restrict__ bias) {
  int tid = blockIdx.x * 256 + threadIdx.x;          // 65536 threads total
  int l = tid & 63;
  int s = (tid >> 6) & 15;
  int n = (tid >> 10) & 31;
  int m = tid >> 15;
  const float* W = m ? Whh : Wih;
  int row = n * 16 + (l & 15);
  int k0  = s * 32 + (l >> 4) * 8;
  const float* src = W + row * E_DIM + k0;
  u16x8 u;
  #pragma unroll
  for (int j = 0; j < 8; ++j) u[j] = f2bf(src[j]);
  *reinterpret_cast<u16x8*>(wpack + (size_t)tid * 8) = u;   // == ((m*32+n)*16+s)*512 + l*8
  if (tid < E_DIM) bias[tid] = bih[tid] + bhh[tid];
}

// ---------------------------------------------------------------------------
// Main fused kernel.
// LDS tiles are [32 rows][512 cols] bf16, XOR-swizzled per 16B unit:
//   idx(row, col) = row*512 + (((col>>3) ^ (row&7)) << 3) + (col&7)
// which makes the A-fragment ds_read_b128 (16 lanes reading 16 rows at the
// same k-range) hit the 8-cycle size floor instead of a 16-way conflict (G4).
// ---------------------------------------------------------------------------
__global__ __launch_bounds__(NTHR, 1)
void rnnpool_kernel(const float* __restrict__ x,
                    const unsigned short* __restrict__ wpack,
                    const float* __restrict__ bias,
                    float* __restrict__ out) {
  __shared__ unsigned short x_lds[R_WIN * E_DIM];   // 32 KB
  __shared__ unsigned short h_hi[R_WIN * E_DIM];    // 32 KB
  __shared__ unsigned short h_lo[R_WIN * E_DIM];    // 32 KB (bf16 residual of h)

  const int tid  = threadIdx.x;
  const int lane = tid & 63;
  const int wid  = tid >> 6;          // 0..7
  const int w0   = blockIdx.x * R_WIN;

  const int l15 = lane & 15;
  const int a5  = lane >> 4;          // 0..3
  const int nt0 = wid * 4;            // each wave: 4 N-tiles = 64 output cols

  float bias_r[4];
  #pragma unroll
  for (int n = 0; n < 4; ++n) bias_r[n] = bias[(nt0 + n) * 16 + l15];

  const unsigned short* wpI = wpack + nt0 * 8192 + lane * 8;   // W_ih frags
  const unsigned short* wpH = wpI + 262144;                    // W_hh frags

  const int srow = tid >> 4;          // staging: row 0..31
  const int sc4  = tid & 15;          // float4 index within row

  for (int t = 0; t < KSIZE; ++t) {
    // ---- stage x_t: fp32 global -> bf16 swizzled LDS (coalesced 1KB/instr) ----
    {
      const float4* src4 = reinterpret_cast<const float4*>(
          x + (size_t)((w0 + srow) * KSIZE + t) * E_DIM);
      #pragma unroll
      for (int j = 0; j < 8; ++j) {
        float4 v = src4[sc4 + 16 * j];
        int col  = (sc4 + 16 * j) * 4;
        int idx  = srow * E_DIM + (((col >> 3) ^ (srow & 7)) << 3) + (col & 7);
        u16x4 u;
        u[0] = f2bf(v.x); u[1] = f2bf(v.y); u[2] = f2bf(v.z); u[3] = f2bf(v.w);
        *reinterpret_cast<u16x4*>(&x_lds[idx]) = u;
      }
    }
    __syncthreads();   // stage + previous-step h writes visible to all waves

    f32x4 acc[2][4];   // [M-tile][N-tile], fully unrolled -> registers
    #pragma unroll
    for (int mt = 0; mt < 2; ++mt)
      #pragma unroll
      for (int n = 0; n < 4; ++n) acc[mt][n] = (f32x4){0.f, 0.f, 0.f, 0.f};

    // ---- x_t @ W_ih^T : K=512 in 16 slices of 32 ----
    #pragma unroll
    for (int s = 0; s < 16; ++s) {
      int u0 = s * 4 + a5;                       // 16B-unit index for this lane
      int ia = l15 * E_DIM + ((u0 ^ (l15 & 7)) << 3);
      bf16x8 A0 = *reinterpret_cast<const bf16x8*>(&x_lds[ia]);
      bf16x8 A1 = *reinterpret_cast<const bf16x8*>(&x_lds[ia + 16 * E_DIM]);
      #pragma unroll
      for (int n = 0; n < 4; ++n) {
        bf16x8 Bf = *reinterpret_cast<const bf16x8*>(wpI + n * 8192 + s * 512);
        acc[0][n] = __builtin_amdgcn_mfma_f32_16x16x32_bf16(A0, Bf, acc[0][n], 0, 0, 0);
        acc[1][n] = __builtin_amdgcn_mfma_f32_16x16x32_bf16(A1, Bf, acc[1][n], 0, 0, 0);
      }
    }

    // ---- h @ W_hh^T (split bf16: hi + residual; B-frag reused for both) ----
    if (t > 0) {
      #pragma unroll
      for (int s = 0; s < 16; ++s) {
        int u0 = s * 4 + a5;
        int ia = l15 * E_DIM + ((u0 ^ (l15 & 7)) << 3);
        bf16x8 H0 = *reinterpret_cast<const bf16x8*>(&h_hi[ia]);
        bf16x8 H1 = *reinterpret_cast<const bf16x8*>(&h_hi[ia + 16 * E_DIM]);
        bf16x8 L0 = *reinterpret_cast<const bf16x8*>(&h_lo[ia]);
        bf16x8 L1 = *reinterpret_cast<const bf16x8*>(&h_lo[ia + 16 * E_DIM]);
        #pragma unroll
        for (int n = 0; n < 4; ++n) {
          bf16x8 Bf = *reinterpret_cast<const bf16x8*>(wpH + n * 8192 + s * 512);
          acc[0][n] = __builtin_amdgcn_mfma_f32_16x16x32_bf16(H0, Bf, acc[0][n], 0, 0, 0);
          acc[1][n] = __builtin_amdgcn_mfma_f32_16x16x32_bf16(H1, Bf, acc[1][n], 0, 0, 0);
          acc[0][n] = __builtin_amdgcn_mfma_f32_16x16x32_bf16(L0, Bf, acc[0][n], 0, 0, 0);
          acc[1][n] = __builtin_amdgcn_mfma_f32_16x16x32_bf16(L1, Bf, acc[1][n], 0, 0, 0);
        }
      }
    }
    __syncthreads();   // all waves done reading h_lds/x_lds before overwrite

    // ---- epilogue: tanh; write h (bf16 hi/lo) or final output (fp32) ----
    // C/D layout (m89-verified): col = lane&15, row = (lane>>4)*4 + reg.
    if (t == KSIZE - 1) {
      #pragma unroll
      for (int mt = 0; mt < 2; ++mt)
        #pragma unroll
        for (int n = 0; n < 4; ++n) {
          int ncol = (nt0 + n) * 16 + l15;
          #pragma unroll
          for (int r = 0; r < 4; ++r) {
            int row = mt * 16 + a5 * 4 + r;
            float th = tanh_fast(acc[mt][n][r] + bias_r[n]);
            out[(size_t)(w0 + row) * E_DIM + ncol] = th;
          }
        }
    } else {
      #pragma unroll
      for (int mt = 0; mt < 2; ++mt)
        #pragma unroll
        for (int n = 0; n < 4; ++n) {
          int ncol = (nt0 + n) * 16 + l15;
          int ub   = ncol >> 3;
          int co   = ncol & 7;
          #pragma unroll
          for (int r = 0; r < 4; ++r) {
            int row = mt * 16 + a5 * 4 + r;
            float th = tanh_fast(acc[mt][n][r] + bias_r[n]);
            unsigned short hi = f2bf(th);
            unsigned short lo = f2bf(th - bf2f(hi));
            int idx = row * E_DIM + ((ub ^ (row & 7)) << 3) + co;
            h_hi[idx] = hi;
            h_lo[idx] = lo;
          }
        }
    }
    // next iteration's top __syncthreads orders these writes before reads
  }
}

extern "C" void kernel_launch(void* const* d_in, const int* in_sizes, int n_in,
                              void* d_out, int out_size, void* d_ws, size_t ws_size,
                              hipStream_t stream) {
  const float* x   = (const float*)d_in[0];
  const float* Wih = (const float*)d_in[1];
  const float* Whh = (const float*)d_in[2];
  const float* bih = (const float*)d_in[3];
  const float* bhh = (const float*)d_in[4];
  float* out = (float*)d_out;

  unsigned short* wpack = (unsigned short*)d_ws;            // 1 MB packed weights
  float* bias = (float*)((char*)d_ws + 524288 * 2);         // 2 KB fused bias

  pack_kernel<<<256, 256, 0, stream>>>(Wih, Whh, bih, bhh, wpack, bias);
  rnnpool_kernel<<<NBLK, NTHR, 0, stream>>>(x, wpack, bias, out);
}

// Round 2
// 280.792 us; speedup vs baseline: 2.0502x; 2.0502x over previous
//
#include <hip/hip_runtime.h>
#include <hip/hip_bf16.h>
#include <stdint.h>

// RNNPool on MI355X: B=16, S=4096, E=512, window=8.
// Two-phase design (round 2):
//   Phase 1 (pre_kernel): PRE = x @ W_ih^T + (b_ih+b_hh), a pure GEMM over
//     2048 independent blocks, output stored fragment-major in d_ws so the
//     recurrence reads its acc-init with coalesced dwordx4 loads.
//   Phase 2 (rec_kernel): h_t = tanh(PRE_t + h@W_hh^T), 256 blocks x 16 waves,
//     h kept in LDS as bf16 hi+lo (split for accuracy), W_hh (512KB) streamed
//     from L2 with 4 waves/SIMD to hide latency.
// Fallback: if ws_size can't hold PRE (136MB), use the round-1 fused kernel.

#define E_DIM 512
#define KSIZE 8
#define R_WIN 32           // windows per block
#define NBLK  256          // 8192 windows / 32

typedef __attribute__((ext_vector_type(8))) short          bf16x8;  // MFMA A/B frag
typedef __attribute__((ext_vector_type(4))) float          f32x4;   // MFMA C/D frag
typedef __attribute__((ext_vector_type(4))) unsigned short u16x4;
typedef __attribute__((ext_vector_type(8))) unsigned short u16x8;

__device__ __forceinline__ unsigned short f2bf(float f) {
  union { float f; uint32_t u; } v; v.f = f;
  uint32_t u = v.u;
  uint32_t r = u + 0x7FFFu + ((u >> 16) & 1u);   // round-to-nearest-even
  return (unsigned short)(r >> 16);
}
__device__ __forceinline__ float bf2f(unsigned short h) {
  union { uint32_t u; float f; } v; v.u = ((uint32_t)h) << 16;
  return v.f;
}
__device__ __forceinline__ float tanh_fast(float v) {
  return 1.0f - 2.0f / (1.0f + __expf(2.0f * v));   // exact saturation, 1 v_exp
}

// ---------------------------------------------------------------------------
// Pack W_ih and W_hh (fp32 [out=512][in=512]) into bf16 fragment-major layout
// for mfma_f32_16x16x32_bf16 B-operand:
//   lane l holds W[n_tile*16 + (l&15)][s*32 + (l>>4)*8 + j], j=0..7
//   ushort index: ((m*32 + n)*16 + s)*512 + l*8
// bias[n] = b_ih[n] + b_hh[n] fp32.
// ---------------------------------------------------------------------------
__global__ void pack_kernel(const float* __restrict__ Wih, const float* __restrict__ Whh,
                            const float* __restrict__ bih, const float* __restrict__ bhh,
                            unsigned short* __restrict__ wpack, float* __restrict__ bias) {
  int tid = blockIdx.x * 256 + threadIdx.x;          // 65536 threads total
  int l = tid & 63;
  int s = (tid >> 6) & 15;
  int n = (tid >> 10) & 31;
  int m = tid >> 15;
  const float* W = m ? Whh : Wih;
  int row = n * 16 + (l & 15);
  int k0  = s * 32 + (l >> 4) * 8;
  const float* src = W + row * E_DIM + k0;
  u16x8 u;
  #pragma unroll
  for (int j = 0; j < 8; ++j) u[j] = f2bf(src[j]);
  *reinterpret_cast<u16x8*>(wpack + (size_t)tid * 8) = u;
  if (tid < E_DIM) bias[tid] = bih[tid] + bhh[tid];
}

// PRE fragment layout: frag id = (((bt)*2 + mt)*32 + nt), bt = b*8+t in [0,2048)
// Each frag = 256 floats = 64 lanes x f32x4 (C/D layout: col=lane&15, row=(lane>>4)*4+r).
#define PRE_FRAG(bt, mt, nt) ((((size_t)(bt) * 2 + (mt)) * 32 + (nt)) * 256)

// ---------------------------------------------------------------------------
// Phase 1: PRE = x_t @ W_ih^T + bias.  Grid 2048 (= 256 window-blocks x 8 t).
// 512 threads = 8 waves, wave owns 4 N-tiles. LDS: bf16 x-tile, XOR-swizzled:
//   idx(row,col) = row*512 + (((col>>3) ^ (row&7))<<3) + (col&7)
// ---------------------------------------------------------------------------
__global__ __launch_bounds__(512, 4)
void pre_kernel(const float* __restrict__ x,
                const unsigned short* __restrict__ wpack,
                const float* __restrict__ bias,
                float* __restrict__ prep) {
  __shared__ unsigned short x_lds[R_WIN * E_DIM];   // 32 KB

  const int bt   = blockIdx.x;
  const int b    = bt >> 3;
  const int t    = bt & 7;
  const int w0   = b * R_WIN;
  const int tid  = threadIdx.x;
  const int lane = tid & 63;
  const int wid  = tid >> 6;          // 0..7
  const int l15  = lane & 15;
  const int a5   = lane >> 4;
  const int nt0  = wid * 4;

  float bias_r[4];
  #pragma unroll
  for (int n = 0; n < 4; ++n) bias_r[n] = bias[(nt0 + n) * 16 + l15];

  const unsigned short* wpI = wpack + nt0 * 8192 + lane * 8;

  // stage x rows (window w0+srow, step t): fp32 -> bf16 swizzled LDS
  {
    const int srow = tid >> 4;
    const int sc4  = tid & 15;
    const float4* src4 = reinterpret_cast<const float4*>(
        x + (size_t)((w0 + srow) * KSIZE + t) * E_DIM);
    #pragma unroll
    for (int j = 0; j < 8; ++j) {
      float4 v = src4[sc4 + 16 * j];
      int col  = (sc4 + 16 * j) * 4;
      int idx  = srow * E_DIM + (((col >> 3) ^ (srow & 7)) << 3) + (col & 7);
      u16x4 u;
      u[0] = f2bf(v.x); u[1] = f2bf(v.y); u[2] = f2bf(v.z); u[3] = f2bf(v.w);
      *reinterpret_cast<u16x4*>(&x_lds[idx]) = u;
    }
  }
  __syncthreads();

  f32x4 acc[2][4];
  #pragma unroll
  for (int mt = 0; mt < 2; ++mt)
    #pragma unroll
    for (int n = 0; n < 4; ++n) acc[mt][n] = (f32x4){0.f, 0.f, 0.f, 0.f};

  #pragma unroll
  for (int s = 0; s < 16; ++s) {
    int u0 = s * 4 + a5;
    int ia = l15 * E_DIM + ((u0 ^ (l15 & 7)) << 3);
    bf16x8 A0 = *reinterpret_cast<const bf16x8*>(&x_lds[ia]);
    bf16x8 A1 = *reinterpret_cast<const bf16x8*>(&x_lds[ia + 16 * E_DIM]);
    #pragma unroll
    for (int n = 0; n < 4; ++n) {
      bf16x8 Bf = *reinterpret_cast<const bf16x8*>(wpI + n * 8192 + s * 512);
      acc[0][n] = __builtin_amdgcn_mfma_f32_16x16x32_bf16(A0, Bf, acc[0][n], 0, 0, 0);
      acc[1][n] = __builtin_amdgcn_mfma_f32_16x16x32_bf16(A1, Bf, acc[1][n], 0, 0, 0);
    }
  }

  // store fragment-major (coalesced dwordx4 per frag)
  #pragma unroll
  for (int mt = 0; mt < 2; ++mt)
    #pragma unroll
    for (int n = 0; n < 4; ++n) {
      f32x4 v = acc[mt][n];
      #pragma unroll
      for (int r = 0; r < 4; ++r) v[r] += bias_r[n];
      *reinterpret_cast<f32x4*>(&prep[PRE_FRAG(bt, mt, nt0 + n) + lane * 4]) = v;
    }
}

// ---------------------------------------------------------------------------
// Phase 2: recurrence. Grid 256, 1024 threads = 16 waves, wave owns 2 N-tiles.
// h in LDS (bf16 hi+lo, XOR-swizzled). W_hh streamed from L2 every step.
// ---------------------------------------------------------------------------
__global__ __launch_bounds__(1024, 4)
void rec_kernel(const float* __restrict__ prep,
                const unsigned short* __restrict__ wpack,
                float* __restrict__ out) {
  __shared__ unsigned short h_hi[R_WIN * E_DIM];    // 32 KB
  __shared__ unsigned short h_lo[R_WIN * E_DIM];    // 32 KB

  const int b    = blockIdx.x;
  const int w0   = b * R_WIN;
  const int tid  = threadIdx.x;
  const int lane = tid & 63;
  const int wid  = tid >> 6;          // 0..15
  const int l15  = lane & 15;
  const int a5   = lane >> 4;
  const int nt0  = wid * 2;

  const unsigned short* wpH = wpack + 262144 + nt0 * 8192 + lane * 8;

  // ---- t = 0: h = tanh(PRE_0) ----
  #pragma unroll
  for (int mt = 0; mt < 2; ++mt)
    #pragma unroll
    for (int n = 0; n < 2; ++n) {
      f32x4 p = *reinterpret_cast<const f32x4*>(
          &prep[PRE_FRAG(b * 8 + 0, mt, nt0 + n) + lane * 4]);
      int ncol = (nt0 + n) * 16 + l15;
      int ub = ncol >> 3, co = ncol & 7;
      #pragma unroll
      for (int r = 0; r < 4; ++r) {
        int row = mt * 16 + a5 * 4 + r;
        float th = tanh_fast(p[r]);
        unsigned short hi = f2bf(th);
        unsigned short lo = f2bf(th - bf2f(hi));
        int idx = row * E_DIM + ((ub ^ (row & 7)) << 3) + co;
        h_hi[idx] = hi;
        h_lo[idx] = lo;
      }
    }

  for (int t = 1; t < KSIZE; ++t) {
    // acc init = PRE_t fragments: pure global loads, issued before the barrier
    // so their latency hides under it (no LDS dependency).
    f32x4 acc[2][2];
    #pragma unroll
    for (int mt = 0; mt < 2; ++mt)
      #pragma unroll
      for (int n = 0; n < 2; ++n)
        acc[mt][n] = *reinterpret_cast<const f32x4*>(
            &prep[PRE_FRAG(b * 8 + t, mt, nt0 + n) + lane * 4]);

    __syncthreads();   // h writes from t-1 visible

    #pragma unroll
    for (int s = 0; s < 16; ++s) {
      int u0 = s * 4 + a5;
      int ia = l15 * E_DIM + ((u0 ^ (l15 & 7)) << 3);
      bf16x8 H0 = *reinterpret_cast<const bf16x8*>(&h_hi[ia]);
      bf16x8 H1 = *reinterpret_cast<const bf16x8*>(&h_hi[ia + 16 * E_DIM]);
      bf16x8 L0 = *reinterpret_cast<const bf16x8*>(&h_lo[ia]);
      bf16x8 L1 = *reinterpret_cast<const bf16x8*>(&h_lo[ia + 16 * E_DIM]);
      #pragma unroll
      for (int n = 0; n < 2; ++n) {
        bf16x8 Bf = *reinterpret_cast<const bf16x8*>(wpH + n * 8192 + s * 512);
        acc[0][n] = __builtin_amdgcn_mfma_f32_16x16x32_bf16(H0, Bf, acc[0][n], 0, 0, 0);
        acc[1][n] = __builtin_amdgcn_mfma_f32_16x16x32_bf16(H1, Bf, acc[1][n], 0, 0, 0);
        acc[0][n] = __builtin_amdgcn_mfma_f32_16x16x32_bf16(L0, Bf, acc[0][n], 0, 0, 0);
        acc[1][n] = __builtin_amdgcn_mfma_f32_16x16x32_bf16(L1, Bf, acc[1][n], 0, 0, 0);
      }
    }
    __syncthreads();   // all waves done reading h before overwrite

    if (t == KSIZE - 1) {
      #pragma unroll
      for (int mt = 0; mt < 2; ++mt)
        #pragma unroll
        for (int n = 0; n < 2; ++n) {
          int ncol = (nt0 + n) * 16 + l15;
          #pragma unroll
          for (int r = 0; r < 4; ++r) {
            int row = mt * 16 + a5 * 4 + r;
            out[(size_t)(w0 + row) * E_DIM + ncol] = tanh_fast(acc[mt][n][r]);
          }
        }
    } else {
      #pragma unroll
      for (int mt = 0; mt < 2; ++mt)
        #pragma unroll
        for (int n = 0; n < 2; ++n) {
          int ncol = (nt0 + n) * 16 + l15;
          int ub = ncol >> 3, co = ncol & 7;
          #pragma unroll
          for (int r = 0; r < 4; ++r) {
            int row = mt * 16 + a5 * 4 + r;
            float th = tanh_fast(acc[mt][n][r]);
            unsigned short hi = f2bf(th);
            unsigned short lo = f2bf(th - bf2f(hi));
            int idx = row * E_DIM + ((ub ^ (row & 7)) << 3) + co;
            h_hi[idx] = hi;
            h_lo[idx] = lo;
          }
        }
    }
  }
}

// ---------------------------------------------------------------------------
// Fallback (round-1 fused kernel) for small ws_size.
// ---------------------------------------------------------------------------
__global__ __launch_bounds__(512, 1)
void rnnpool_fused(const float* __restrict__ x,
                   const unsigned short* __restrict__ wpack,
                   const float* __restrict__ bias,
                   float* __restrict__ out) {
  __shared__ unsigned short x_lds[R_WIN * E_DIM];
  __shared__ unsigned short h_hi[R_WIN * E_DIM];
  __shared__ unsigned short h_lo[R_WIN * E_DIM];

  const int tid  = threadIdx.x;
  const int lane = tid & 63;
  const int wid  = tid >> 6;
  const int w0   = blockIdx.x * R_WIN;
  const int l15 = lane & 15;
  const int a5  = lane >> 4;
  const int nt0 = wid * 4;

  float bias_r[4];
  #pragma unroll
  for (int n = 0; n < 4; ++n) bias_r[n] = bias[(nt0 + n) * 16 + l15];

  const unsigned short* wpI = wpack + nt0 * 8192 + lane * 8;
  const unsigned short* wpH = wpI + 262144;
  const int srow = tid >> 4;
  const int sc4  = tid & 15;

  for (int t = 0; t < KSIZE; ++t) {
    {
      const float4* src4 = reinterpret_cast<const float4*>(
          x + (size_t)((w0 + srow) * KSIZE + t) * E_DIM);
      #pragma unroll
      for (int j = 0; j < 8; ++j) {
        float4 v = src4[sc4 + 16 * j];
        int col  = (sc4 + 16 * j) * 4;
        int idx  = srow * E_DIM + (((col >> 3) ^ (srow & 7)) << 3) + (col & 7);
        u16x4 u;
        u[0] = f2bf(v.x); u[1] = f2bf(v.y); u[2] = f2bf(v.z); u[3] = f2bf(v.w);
        *reinterpret_cast<u16x4*>(&x_lds[idx]) = u;
      }
    }
    __syncthreads();

    f32x4 acc[2][4];
    #pragma unroll
    for (int mt = 0; mt < 2; ++mt)
      #pragma unroll
      for (int n = 0; n < 4; ++n) acc[mt][n] = (f32x4){0.f, 0.f, 0.f, 0.f};

    #pragma unroll
    for (int s = 0; s < 16; ++s) {
      int u0 = s * 4 + a5;
      int ia = l15 * E_DIM + ((u0 ^ (l15 & 7)) << 3);
      bf16x8 A0 = *reinterpret_cast<const bf16x8*>(&x_lds[ia]);
      bf16x8 A1 = *reinterpret_cast<const bf16x8*>(&x_lds[ia + 16 * E_DIM]);
      #pragma unroll
      for (int n = 0; n < 4; ++n) {
        bf16x8 Bf = *reinterpret_cast<const bf16x8*>(wpI + n * 8192 + s * 512);
        acc[0][n] = __builtin_amdgcn_mfma_f32_16x16x32_bf16(A0, Bf, acc[0][n], 0, 0, 0);
        acc[1][n] = __builtin_amdgcn_mfma_f32_16x16x32_bf16(A1, Bf, acc[1][n], 0, 0, 0);
      }
    }

    if (t > 0) {
      #pragma unroll
      for (int s = 0; s < 16; ++s) {
        int u0 = s * 4 + a5;
        int ia = l15 * E_DIM + ((u0 ^ (l15 & 7)) << 3);
        bf16x8 H0 = *reinterpret_cast<const bf16x8*>(&h_hi[ia]);
        bf16x8 H1 = *reinterpret_cast<const bf16x8*>(&h_hi[ia + 16 * E_DIM]);
        bf16x8 L0 = *reinterpret_cast<const bf16x8*>(&h_lo[ia]);
        bf16x8 L1 = *reinterpret_cast<const bf16x8*>(&h_lo[ia + 16 * E_DIM]);
        #pragma unroll
        for (int n = 0; n < 4; ++n) {
          bf16x8 Bf = *reinterpret_cast<const bf16x8*>(wpH + n * 8192 + s * 512);
          acc[0][n] = __builtin_amdgcn_mfma_f32_16x16x32_bf16(H0, Bf, acc[0][n], 0, 0, 0);
          acc[1][n] = __builtin_amdgcn_mfma_f32_16x16x32_bf16(H1, Bf, acc[1][n], 0, 0, 0);
          acc[0][n] = __builtin_amdgcn_mfma_f32_16x16x32_bf16(L0, Bf, acc[0][n], 0, 0, 0);
          acc[1][n] = __builtin_amdgcn_mfma_f32_16x16x32_bf16(L1, Bf, acc[1][n], 0, 0, 0);
        }
      }
    }
    __syncthreads();

    if (t == KSIZE - 1) {
      #pragma unroll
      for (int mt = 0; mt < 2; ++mt)
        #pragma unroll
        for (int n = 0; n < 4; ++n) {
          int ncol = (nt0 + n) * 16 + l15;
          #pragma unroll
          for (int r = 0; r < 4; ++r) {
            int row = mt * 16 + a5 * 4 + r;
            out[(size_t)(w0 + row) * E_DIM + ncol] = tanh_fast(acc[mt][n][r] + bias_r[n]);
          }
        }
    } else {
      #pragma unroll
      for (int mt = 0; mt < 2; ++mt)
        #pragma unroll
        for (int n = 0; n < 4; ++n) {
          int ncol = (nt0 + n) * 16 + l15;
          int ub = ncol >> 3, co = ncol & 7;
          #pragma unroll
          for (int r = 0; r < 4; ++r) {
            int row = mt * 16 + a5 * 4 + r;
            float th = tanh_fast(acc[mt][n][r] + bias_r[n]);
            unsigned short hi = f2bf(th);
            unsigned short lo = f2bf(th - bf2f(hi));
            int idx = row * E_DIM + ((ub ^ (row & 7)) << 3) + co;
            h_hi[idx] = hi;
            h_lo[idx] = lo;
          }
        }
    }
  }
}

extern "C" void kernel_launch(void* const* d_in, const int* in_sizes, int n_in,
                              void* d_out, int out_size, void* d_ws, size_t ws_size,
                              hipStream_t stream) {
  const float* x   = (const float*)d_in[0];
  const float* Wih = (const float*)d_in[1];
  const float* Whh = (const float*)d_in[2];
  const float* bih = (const float*)d_in[3];
  const float* bhh = (const float*)d_in[4];
  float* out = (float*)d_out;

  const size_t PRE_BYTES  = (size_t)33554432 * 4;      // 134.2 MB
  const size_t WPK_BYTES  = (size_t)524288 * 2;        // 1 MB
  const size_t NEED       = PRE_BYTES + WPK_BYTES + 4096;

  if (ws_size >= NEED) {
    float*          prep  = (float*)d_ws;
    unsigned short* wpack = (unsigned short*)((char*)d_ws + PRE_BYTES);
    float*          bias  = (float*)((char*)d_ws + PRE_BYTES + WPK_BYTES);
    pack_kernel<<<256, 256, 0, stream>>>(Wih, Whh, bih, bhh, wpack, bias);
    pre_kernel<<<2048, 512, 0, stream>>>(x, wpack, bias, prep);
    rec_kernel<<<NBLK, 1024, 0, stream>>>(prep, wpack, out);
  } else {
    unsigned short* wpack = (unsigned short*)d_ws;
    float*          bias  = (float*)((char*)d_ws + WPK_BYTES);
    pack_kernel<<<256, 256, 0, stream>>>(Wih, Whh, bih, bhh, wpack, bias);
    rnnpool_fused<<<NBLK, 512, 0, stream>>>(x, wpack, bias, out);
  }
}